// Round 2
// 1291.820 us; speedup vs baseline: 1.1819x; 1.1819x over previous
//
#include <hip/hip_runtime.h>
#include <stdint.h>

// LSTM autoregressive rollout, batch-split persistent blocks.
// B=8192, HORIZON=64, F=64, ORDER=16, K=256, 4K=1024.
// Block = 32 batch rows, 512 threads (8 waves, 2/SIMD). 256 blocks = 1/CU.
// Weights pre-swizzled to bf16 B-fragment order in d_ws (704KB).
// Weight k-step 0 parked in registers (64KB/CU), k-steps 1-2 parked in
// LDS (128KB/CU); only ks 3..10 (524KB/step) streamed from L2 per timestep.
// x_{t+1} prefetched during the GEMM phase.
// Streamed double-buffer fully explicit (no pointer-select over local arrays).
// K rows layout: 0..63 = x_t, 64..79 = yp (newest first), 80..335 = h, 336..351 pad.

typedef short v8s __attribute__((ext_vector_type(8)));
typedef float v4f __attribute__((ext_vector_type(4)));

#define NKS 11          // 352/32 k-steps
#define NKCOL 1024      // 4K columns
#define PKR 1           // k-steps parked in registers (ks 0)
#define PKL 2           // k-steps parked in LDS (ks 1..2)
#define SK0 (PKR + PKL) // first streamed k-step (3)

__device__ __forceinline__ unsigned bf16u(float f) {
  unsigned u = __float_as_uint(f);
  return (u + 0x7FFFu + ((u >> 16) & 1u)) >> 16;   // RNE fp32->bf16
}
__device__ __forceinline__ float sigm(float x) {
  return __builtin_amdgcn_rcpf(1.f + __expf(-x));
}
__device__ __forceinline__ float tanh_(float x) {
  return 1.f - 2.f * __builtin_amdgcn_rcpf(1.f + __expf(2.f * x));
}
// Swizzled A-LDS address for element (m, k): tiles of 1KB per (mt, ks),
// within tile lane-linear for the MFMA A-fragment read (lane*16B).
__device__ __forceinline__ int a_addr(int m, int k) {
  return (((m >> 4) * NKS + (k >> 5)) << 10)
       + ((((k >> 3) & 3) * 16 + (m & 15)) << 4)
       + ((k & 7) << 1);
}

// ---------------- weight swizzle prep (once per launch) ----------------
// Wsw[(nt*11 + ks)*64 + lane] = 8 bf16: B[k = ks*32 + (lane>>4)*8 + j][n = nt*16 + (lane&15)]
__global__ void prep_w(const float* __restrict__ ker, const float* __restrict__ rec,
                       uint4* __restrict__ wsw) {
  int tid = blockIdx.x * 256 + threadIdx.x;     // 0 .. 45055 (64 nt * 11 ks * 64 lanes)
  int lane = tid & 63;
  int rest = tid >> 6;
  int ks = rest % NKS;
  int nt = rest / NKS;
  int n  = nt * 16 + (lane & 15);
  int k0 = ks * 32 + ((lane >> 4) & 3) * 8;
  unsigned h[8];
  #pragma unroll
  for (int j = 0; j < 8; ++j) {
    int k = k0 + j;
    float v = 0.f;
    if (k < 80)       v = ker[k * NKCOL + n];          // x rows 0..63, yp rows 64..79
    else if (k < 336) v = rec[(k - 80) * NKCOL + n];   // h rows
    h[j] = bf16u(v);
  }
  uint4 o;
  o.x = h[0] | (h[1] << 16); o.y = h[2] | (h[3] << 16);
  o.z = h[4] | (h[5] << 16); o.w = h[6] | (h[7] << 16);
  wsw[tid] = o;
}

// ---------------- main persistent kernel ----------------
__global__ __launch_bounds__(512, 2)
void lstm_main(const float* __restrict__ x, const float* __restrict__ y0,
               const float* __restrict__ bias, const float* __restrict__ dw,
               const float* __restrict__ db, const v8s* __restrict__ wv,
               float* __restrict__ out) {
  __shared__ __align__(16) char a_lds[2 * NKS * 1024];   // 22528 B swizzled A
  __shared__ __align__(16) v8s w_lds[PKL * 64 * 64];     // 131072 B parked W (ks 1..2)
  __shared__ float predbuf[32][8];
  __shared__ float predf[32];

  const int tid  = threadIdx.x;
  const int lane = tid & 63;
  const int wave = tid >> 6;
  const int l15  = lane & 15;
  const int quad = lane >> 4;
  const int b0   = blockIdx.x * 32;

  // zero A (h rows must be 0 at t=0; pad rows stay 0 forever)
  for (int i = tid; i < 2 * NKS * 256; i += 512) ((unsigned*)a_lds)[i] = 0;
  // park W k-steps 1..2 into LDS: w_lds[ksl*4096 + nt*64 + lane]
  for (int i = tid; i < PKL * 64 * 64; i += 512) {
    int ksl = i >> 12;
    int nt  = (i >> 6) & 63;
    int ln  = i & 63;
    w_lds[i] = wv[(nt * NKS + PKR + ksl) * 64 + ln];
  }

  // per-lane constants: wave owns hidden units [wave*32, wave*32+32)
  // local ntile ln = gate*2 + s  ->  global ntile = gate*16 + wave*2 + s
  float bias_v[8];
  int wb[8], wlo[8];
  #pragma unroll
  for (int ln = 0; ln < 8; ++ln) {
    int g = ln >> 1, s = ln & 1;
    int ntg = g * 16 + wave * 2 + s;
    wb[ln]  = ntg * NKS * 64;
    wlo[ln] = ntg * 64 + lane;
    bias_v[ln] = bias[ntg * 16 + l15];
  }
  float dw_v[2];
  dw_v[0] = dw[wave * 32 + l15];
  dw_v[1] = dw[wave * 32 + 16 + l15];
  const float dbv = db[0];

  // park W k-step 0 in registers (persistent across all timesteps)
  v8s wreg[8];
  #pragma unroll
  for (int ln = 0; ln < 8; ++ln)
    wreg[ln] = wv[wb[ln] + lane];

  float cst[2][2][4];           // c state: [mt][s][r]
  #pragma unroll
  for (int mt = 0; mt < 2; ++mt)
    #pragma unroll
    for (int s = 0; s < 2; ++s)
      #pragma unroll
      for (int r = 0; r < 4; ++r) cst[mt][s][r] = 0.f;

  // x prefetch for t=0 (waves 0-3)
  const int ms_x  = tid >> 3;          // valid for tid < 256
  const int kq8_x = tid & 7;
  const int ms_y  = (tid - 256) >> 3;  // valid for tid >= 256
  const int jj    = tid & 7;
  float4 xpa, xpb;
  if (tid < 256) {
    const float* xp = x + ((size_t)((b0 + ms_x) * 64)) * 64 + kq8_x * 8;
    xpa = ((const float4*)xp)[0];
    xpb = ((const float4*)xp)[1];
  }

  __syncthreads();

  #pragma unroll 1
  for (int t = 0; t < 64; ++t) {
    // ---- P1: read phase (x already in regs; yp olds / y0; prev pred) ----
    unsigned xw[4];
    unsigned short q0 = 0, q1 = 0;
    float pin = 0.f;
    if (tid < 256) {                       // waves 0-3: convert prefetched x_t
      xw[0] = bf16u(xpa.x) | (bf16u(xpa.y) << 16);
      xw[1] = bf16u(xpa.z) | (bf16u(xpa.w) << 16);
      xw[2] = bf16u(xpb.x) | (bf16u(xpb.y) << 16);
      xw[3] = bf16u(xpb.z) | (bf16u(xpb.w) << 16);
    } else {                               // waves 4-7: yp shift / init
      if (t == 0) {
        q0 = (unsigned short)bf16u(y0[(b0 + ms_y) * 16 + 2 * jj]);
        q1 = (unsigned short)bf16u(y0[(b0 + ms_y) * 16 + 2 * jj + 1]);
      } else {
        q0 = *(const unsigned short*)(a_lds + a_addr(ms_y, 64 + 2 * jj));
        q1 = *(const unsigned short*)(a_lds + a_addr(ms_y, 64 + 2 * jj + 1));
        pin = predf[ms_y];
      }
    }
    __syncthreads();
    // ---- P2: write phase ----
    if (tid < 256) {
      uint4 w4; w4.x = xw[0]; w4.y = xw[1]; w4.z = xw[2]; w4.w = xw[3];
      *(uint4*)(a_lds + a_addr(ms_x, kq8_x * 8)) = w4;
    } else {
      if (t == 0) {
        *(unsigned short*)(a_lds + a_addr(ms_y, 64 + 2 * jj))     = q0;
        *(unsigned short*)(a_lds + a_addr(ms_y, 64 + 2 * jj + 1)) = q1;
      } else {
        if (jj < 7) {
          *(unsigned short*)(a_lds + a_addr(ms_y, 64 + 2 * jj + 1)) = q0;
          *(unsigned short*)(a_lds + a_addr(ms_y, 64 + 2 * jj + 2)) = q1;
        } else {
          *(unsigned short*)(a_lds + a_addr(ms_y, 79)) = q0;   // j=14 -> 15
        }
        if (jj == 0)
          *(unsigned short*)(a_lds + a_addr(ms_y, 64)) = (unsigned short)bf16u(pin);
      }
    }
    __syncthreads();

    // ---- GEMM phase: also prefetch x_{t+1} (independent, hides HBM latency) ----
    if (t < 63 && tid < 256) {
      const float* xp = x + ((size_t)((b0 + ms_x) * 64 + (t + 1))) * 64 + kq8_x * 8;
      xpa = ((const float4*)xp)[0];
      xpb = ((const float4*)xp)[1];
    }

    // ---- P3: GEMM  z[32,1024] += inp[32,352] @ W[352,1024] ----
    v4f acc[2][8];
    #pragma unroll
    for (int mt = 0; mt < 2; ++mt)
      #pragma unroll
      for (int ln = 0; ln < 8; ++ln) acc[mt][ln] = v4f{0.f, 0.f, 0.f, 0.f};

    v8s bs0[8], bs1[8];
    #pragma unroll
    for (int ln = 0; ln < 8; ++ln) bs0[ln] = wv[wb[ln] + SK0 * 64 + lane];
    v8s af0 = *(const v8s*)(a_lds + (lane << 4));
    v8s af1 = *(const v8s*)(a_lds + (NKS << 10) + (lane << 4));

    // A-fragment prefetch + 16 MFMA on weight fragments W8, for tile ks.
    #define MFMA_BLK(ksi, W8)                                                   \
      do {                                                                      \
        v8s c0 = af0, c1 = af1;                                                 \
        if ((ksi) < NKS - 1) {                                                  \
          af0 = *(const v8s*)(a_lds + (((ksi) + 1) << 10) + (lane << 4));       \
          af1 = *(const v8s*)(a_lds + ((NKS + (ksi) + 1) << 10) + (lane << 4)); \
        }                                                                       \
        _Pragma("unroll")                                                       \
        for (int ln = 0; ln < 8; ++ln) {                                        \
          acc[0][ln] = __builtin_amdgcn_mfma_f32_16x16x32_bf16(c0, W8[ln], acc[0][ln], 0, 0, 0); \
          acc[1][ln] = __builtin_amdgcn_mfma_f32_16x16x32_bf16(c1, W8[ln], acc[1][ln], 0, 0, 0); \
        }                                                                       \
      } while (0)
    #define REFILL(BUF, rks)                                                    \
      do {                                                                      \
        _Pragma("unroll")                                                       \
        for (int ln = 0; ln < 8; ++ln)                                          \
          BUF[ln] = wv[wb[ln] + (rks) * 64 + lane];                             \
      } while (0)

    // ks = 0: register-parked weights (no loads at all)
    MFMA_BLK(0, wreg);

    // ks = 1..2: LDS-parked weights; issue bs1 <- ks 4 under cover
    {
      v8s wl[8];
      #pragma unroll
      for (int ln = 0; ln < 8; ++ln) wl[ln] = w_lds[wlo[ln]];
      REFILL(bs1, SK0 + 1);
      MFMA_BLK(1, wl);
      #pragma unroll
      for (int ln = 0; ln < 8; ++ln) wl[ln] = w_lds[4096 + wlo[ln]];
      MFMA_BLK(2, wl);
    }

    // ks = 3..10: streamed, explicit double-buffer, consume-then-refill
    MFMA_BLK(3, bs0);  REFILL(bs0, 5);
    MFMA_BLK(4, bs1);  REFILL(bs1, 6);
    MFMA_BLK(5, bs0);  REFILL(bs0, 7);
    MFMA_BLK(6, bs1);  REFILL(bs1, 8);
    MFMA_BLK(7, bs0);  REFILL(bs0, 9);
    MFMA_BLK(8, bs1);  REFILL(bs1, 10);
    MFMA_BLK(9, bs0);
    MFMA_BLK(10, bs1);

    #undef MFMA_BLK
    #undef REFILL

    __syncthreads();   // all A reads done before h-row writes

    // ---- P4: gates, c/h update, h->A, pred partials ----
    float padd[2][4];
    #pragma unroll
    for (int mt = 0; mt < 2; ++mt)
      #pragma unroll
      for (int r = 0; r < 4; ++r) padd[mt][r] = 0.f;

    #pragma unroll
    for (int mt = 0; mt < 2; ++mt) {
      #pragma unroll
      for (int s = 0; s < 2; ++s) {
        const int kk = 80 + wave * 32 + s * 16 + l15;    // h row in A
        #pragma unroll
        for (int r = 0; r < 4; ++r) {
          float zi = acc[mt][0 + s][r] + bias_v[0 + s];
          float zf = acc[mt][2 + s][r] + bias_v[2 + s];
          float zg = acc[mt][4 + s][r] + bias_v[4 + s];
          float zo = acc[mt][6 + s][r] + bias_v[6 + s];
          float is = sigm(zi), fs = sigm(zf), gs = tanh_(zg), os = sigm(zo);
          float cn = fs * cst[mt][s][r] + is * gs;
          cst[mt][s][r] = cn;
          float hh = os * tanh_(cn);
          int m = mt * 16 + quad * 4 + r;
          *(unsigned short*)(a_lds + a_addr(m, kk)) = (unsigned short)bf16u(hh);
          padd[mt][r] += hh * dw_v[s];
        }
      }
    }
    // reduce pred partial over the 16-lane column group
    #pragma unroll
    for (int mt = 0; mt < 2; ++mt) {
      #pragma unroll
      for (int r = 0; r < 4; ++r) {
        float p = padd[mt][r];
        p += __shfl_xor(p, 1);
        p += __shfl_xor(p, 2);
        p += __shfl_xor(p, 4);
        p += __shfl_xor(p, 8);
        if (l15 == 0) predbuf[mt * 16 + quad * 4 + r][wave] = p;
      }
    }
    __syncthreads();
    // ---- P5: finalize pred, write output ----
    if (tid < 32) {
      float p = dbv;
      #pragma unroll
      for (int w = 0; w < 8; ++w) p += predbuf[tid][w];
      out[(size_t)(b0 + tid) * 64 + t] = p;
      predf[tid] = p;
    }
    __syncthreads();
  }
}

extern "C" void kernel_launch(void* const* d_in, const int* in_sizes, int n_in,
                              void* d_out, int out_size, void* d_ws, size_t ws_size,
                              hipStream_t stream) {
  const float* x    = (const float*)d_in[0];
  const float* y0   = (const float*)d_in[1];
  const float* ker  = (const float*)d_in[2];
  const float* rec  = (const float*)d_in[3];
  const float* bias = (const float*)d_in[4];
  const float* dw   = (const float*)d_in[5];
  const float* db   = (const float*)d_in[6];

  // swizzled weights: 64 ntiles * 11 ksteps * 64 lanes * 16B = 720896 B in d_ws
  prep_w<<<dim3(176), dim3(256), 0, stream>>>(ker, rec, (uint4*)d_ws);
  lstm_main<<<dim3(256), dim3(512), 0, stream>>>(x, y0, bias, dw, db,
                                                 (const v8s*)d_ws, (float*)d_out);
}